// Round 5
// baseline (345.510 us; speedup 1.0000x reference)
//
#include <hip/hip_runtime.h>
#include <math.h>

typedef unsigned short u16;
typedef unsigned int u32;
typedef __bf16 bf16x8 __attribute__((ext_vector_type(8)));
typedef float f32x4 __attribute__((ext_vector_type(4)));
typedef u32 u32x4 __attribute__((ext_vector_type(4)));

#define NB 4
#define SS 2048
#define DD 768
#define HH 12
#define HD 64
#define ROWS (NB*SS)   // 8192

__device__ __forceinline__ u16 f2bf(float f) {
    union { float f; unsigned u; } v; v.f = f;
    unsigned r = v.u + 0x7fffu + ((v.u >> 16) & 1u);
    return (u16)(r >> 16);
}
__device__ __forceinline__ u32 fas(float f) { union { float f; u32 u; } v; v.f = f; return v.u; }

__device__ __forceinline__ void gl_lds16(const void* g, void* l) {
    __builtin_amdgcn_global_load_lds((__attribute__((address_space(1))) void*)(g),
                                     (__attribute__((address_space(3))) void*)(l),
                                     16, 0, 0);
}

// ---------------- fused prep: all f32->bf16 casts + valid-key scan ----------------
// Blocks [0,13056): vectorized casts. Blocks [13056,13060): per-batch prefix
// scan of the key mask -> cidx (compacted position or -1) and cnt.
__global__ __launch_bounds__(256) void prep_kernel(
        const float* __restrict__ X, const float* __restrict__ Wq,
        const float* __restrict__ Wk, const float* __restrict__ Wv,
        const float* __restrict__ Wo, const float* __restrict__ W1,
        const float* __restrict__ W2, const int* __restrict__ mask,
        u16* __restrict__ Xb, u16* __restrict__ Wqkvb, u16* __restrict__ Wob,
        u16* __restrict__ W1b, u16* __restrict__ W2b,
        int* __restrict__ cidx, int* __restrict__ cnt) {
    const int blk = blockIdx.x, tid = threadIdx.x;
    const float* src; u16* dst; int idx;
    if (blk < 6144)       { src = X;  dst = Xb;               idx = blk * 1024 + tid * 4; }
    else if (blk < 6720)  { src = Wq; dst = Wqkvb;            idx = (blk - 6144) * 1024 + tid * 4; }
    else if (blk < 7296)  { src = Wk; dst = Wqkvb + DD * DD;  idx = (blk - 6720) * 1024 + tid * 4; }
    else if (blk < 7872)  { src = Wv; dst = Wqkvb + 2*DD*DD;  idx = (blk - 7296) * 1024 + tid * 4; }
    else if (blk < 8448)  { src = Wo; dst = Wob;              idx = (blk - 7872) * 1024 + tid * 4; }
    else if (blk < 10752) { src = W1; dst = W1b;              idx = (blk - 8448) * 1024 + tid * 4; }
    else if (blk < 13056) { src = W2; dst = W2b;              idx = (blk - 10752) * 1024 + tid * 4; }
    else {
        // scan block: b = blk - 13056
        const int b = blk - 13056;
        const int lane = tid & 63, wave = tid >> 6;
        const int base = b * SS + tid * 8;
        int4 m0 = *(const int4*)&mask[base];
        int4 m1 = *(const int4*)&mask[base + 4];
        int v[8] = { m0.x != 0, m0.y != 0, m0.z != 0, m0.w != 0,
                     m1.x != 0, m1.y != 0, m1.z != 0, m1.w != 0 };
        int own = 0;
#pragma unroll
        for (int i = 0; i < 8; ++i) own += v[i];
        int inc = own;
#pragma unroll
        for (int o = 1; o < 64; o <<= 1) {
            int n = __shfl_up(inc, o);
            if (lane >= o) inc += n;
        }
        __shared__ int wsum[4];
        if (lane == 63) wsum[wave] = inc;
        __syncthreads();
        int wbase = 0;
#pragma unroll
        for (int w = 0; w < 4; ++w) wbase += (w < wave) ? wsum[w] : 0;
        int pos = wbase + inc - own;   // exclusive prefix
        int o8[8];
#pragma unroll
        for (int i = 0; i < 8; ++i) { o8[i] = v[i] ? pos : -1; pos += v[i]; }
        *(int4*)&cidx[base]     = make_int4(o8[0], o8[1], o8[2], o8[3]);
        *(int4*)&cidx[base + 4] = make_int4(o8[4], o8[5], o8[6], o8[7]);
        if (tid == 255) cnt[b] = wbase + inc;
        return;
    }
    float4 v = *(const float4*)&src[idx];
    ushort4 o;
    o.x = f2bf(v.x); o.y = f2bf(v.y); o.z = f2bf(v.z); o.w = f2bf(v.w);
    *(ushort4*)&dst[idx] = o;
}

// ---------------- GEMM: C[M,N] = A[M,K] (bf16) * B[N,K]^T (bf16) ----------------
// 128xBN tile, BK=64, 4 waves, chunk-swizzled LDS (phys = c ^ (row&7)).
// Double-buffered staging with counted vmcnt (T3-min + T4): next K-tile's
// global_load_lds stay in flight across the compute phase; never drain to 0
// in the main loop. setprio(1) around the MFMA cluster (T5).
// 1D grid, XCD-slab mapping: xcd = id&7 owns m-blocks [xcd*8, xcd*8+8) x all n.
// EPI 0: scatter Q + gather-compact K/V | 1: tanh-GELU bf16 | 2: +auxF f32 | 3: +auxB f32
template <int EPI, int BN>
__global__ __launch_bounds__(256) void gemm_bt(const u16* __restrict__ A,
                                               const u16* __restrict__ B,
                                               int M, int N, int K,
                                               void* __restrict__ out,
                                               const void* __restrict__ aux,
                                               u16* __restrict__ Qb,
                                               u16* __restrict__ Kb,
                                               u16* __restrict__ Vb,
                                               const int* __restrict__ cidx) {
    __shared__ __align__(16) u16 lA[2][128 * 64];
    __shared__ __align__(16) u16 lB[2][BN * 64];
    constexpr int MI = (BN == 128) ? 4 : 2;
    const int tid = threadIdx.x;
    const int lane = tid & 63, wave = tid >> 6;
    const int quad = lane >> 4, lc = lane & 15;
    const int xcd = blockIdx.x & 7, loc = blockIdx.x >> 3;
    const int mb = xcd * 8 + (loc & 7), nb = loc >> 3;   // M=8192 fixed: 64 m-blocks
    const int m0 = mb * 128, n0 = nb * BN;
    const int wrow = (BN == 128) ? (wave >> 1) * 64 : wave * 32;
    const int wcol = (BN == 128) ? (wave & 1) * 64 : 0;
    const int swz = lc & 7;

    auto stage = [&](int bi, int kb) {
#pragma unroll
        for (int p0 = 0; p0 < 1024; p0 += 256) {
            int p = p0 + tid, row = p >> 3, cl = (p & 7) ^ (row & 7);
            gl_lds16(A + (size_t)(m0 + row) * K + kb + cl * 8, &lA[bi][(size_t)(p0 + wave * 64) * 8]);
        }
#pragma unroll
        for (int p0 = 0; p0 < BN * 8; p0 += 256) {
            int p = p0 + tid, row = p >> 3, cl = (p & 7) ^ (row & 7);
            gl_lds16(B + (size_t)(n0 + row) * K + kb + cl * 8, &lB[bi][(size_t)(p0 + wave * 64) * 8]);
        }
    };

    f32x4 acc[MI][4] = {};
    const int KT = K >> 6;

    stage(0, 0);
    for (int t = 0; t < KT; ++t) {
        const int cur = t & 1;
        if (t < KT - 1) {
            stage(cur ^ 1, (t + 1) << 6);
            __builtin_amdgcn_sched_barrier(0);
            if constexpr (BN == 128) asm volatile("s_waitcnt vmcnt(8)" ::: "memory");
            else                     asm volatile("s_waitcnt vmcnt(6)" ::: "memory");
        } else {
            __builtin_amdgcn_sched_barrier(0);
            asm volatile("s_waitcnt vmcnt(0)" ::: "memory");
        }
        __builtin_amdgcn_sched_barrier(0);
        __builtin_amdgcn_s_barrier();
        __builtin_amdgcn_sched_barrier(0);

        const u16* bA = &lA[cur][0];
        const u16* bB = &lB[cur][0];
#pragma unroll
        for (int k2 = 0; k2 < 2; ++k2) {
            bf16x8 af[MI], bfr[4];
#pragma unroll
            for (int t_ = 0; t_ < MI; ++t_)
                af[t_] = *(const bf16x8*)&bA[(wrow + t_ * 16 + lc) * 64 + ((quad + k2 * 4) ^ swz) * 8];
#pragma unroll
            for (int t_ = 0; t_ < 4; ++t_)
                bfr[t_] = *(const bf16x8*)&bB[(wcol + t_ * 16 + lc) * 64 + ((quad + k2 * 4) ^ swz) * 8];
            __builtin_amdgcn_s_setprio(1);
#pragma unroll
            for (int mi = 0; mi < MI; ++mi)
#pragma unroll
                for (int ni = 0; ni < 4; ++ni)
                    acc[mi][ni] = __builtin_amdgcn_mfma_f32_16x16x32_bf16(af[mi], bfr[ni],
                                                                         acc[mi][ni], 0, 0, 0);
            __builtin_amdgcn_s_setprio(0);
        }
        __builtin_amdgcn_sched_barrier(0);
        __builtin_amdgcn_s_barrier();   // all reads of buf[cur] done before next stage overwrites
    }

#pragma unroll
    for (int mi = 0; mi < MI; ++mi) {
        int csa[4];
        if constexpr (EPI == 0) {
            int mbase = m0 + wrow + mi * 16 + quad * 4;
            int4 cs4 = *(const int4*)&cidx[(mbase >> 11) * SS + (mbase & 2047)];
            csa[0] = cs4.x; csa[1] = cs4.y; csa[2] = cs4.z; csa[3] = cs4.w;
        }
#pragma unroll
        for (int r = 0; r < 4; ++r) {
            int m = m0 + wrow + mi * 16 + quad * 4 + r;
#pragma unroll
            for (int ni = 0; ni < 4; ++ni) {
                int n = n0 + wcol + ni * 16 + lc;
                float v = acc[mi][ni][r];
                if constexpr (EPI == 0) {
                    int b = m >> 11, s = m & 2047;
                    int which = n / DD, rem = n - which * DD;
                    int h = rem >> 6, d = rem & 63;
                    u16* dst = which == 0 ? Qb : (which == 1 ? Kb : Vb);
                    int sidx = which == 0 ? s : csa[r];   // K/V: gather-compact
                    if (sidx >= 0)
                        dst[((((size_t)b * HH + h) * SS + sidx) << 6) + d] = f2bf(v);
                } else if constexpr (EPI == 1) {
                    // gelu_tanh(v) = v * sigmoid(2*0.79788456*(v + 0.044715 v^3))
                    float u = v * fmaf(v * v, 0.035677408f, 0.7978845608f);
                    float e = __builtin_amdgcn_exp2f(u * 2.885390082f);  // e^{2u}
                    float g = v - v * __builtin_amdgcn_rcpf(e + 1.0f);
                    ((u16*)out)[(size_t)m * N + n] = f2bf(g);
                } else if constexpr (EPI == 2) {
                    ((float*)out)[(size_t)m * N + n] =
                        v + ((const float*)aux)[(size_t)m * N + n];
                } else {
                    ((float*)out)[(size_t)m * N + n] =
                        v + (float)(((const __bf16*)aux)[(size_t)m * N + n]);
                }
            }
        }
    }
}

// ---------------- V transpose: compact [B,H,S,D] -> [B,H,D,S], zero-pad to 64 ----------------
__global__ __launch_bounds__(256) void transpose_v(const u16* __restrict__ V,
                                                   u16* __restrict__ Vt,
                                                   const int* __restrict__ cnt) {
    __shared__ u16 t[32][33];
    int bh = blockIdx.z;
    int c = cnt[bh / HH];
    int cr = (c + 63) & ~63;
    int s0 = blockIdx.x * 32, d0 = blockIdx.y * 32;
    if (s0 >= cr) return;
    const u16* vb = V + (size_t)bh * SS * HD;
    u16* vtb = Vt + (size_t)bh * HD * SS;
    int tx = threadIdx.x & 31, ty = threadIdx.x >> 5;
#pragma unroll
    for (int i = 0; i < 32; i += 8) {
        int s = s0 + ty + i;
        t[ty + i][tx] = (s < c) ? vb[(size_t)s * HD + d0 + tx] : (u16)0;
    }
    __syncthreads();
#pragma unroll
    for (int i = 0; i < 32; i += 8) vtb[(size_t)(d0 + ty + i) * SS + s0 + tx] = t[tx][ty + i];
}

// ---------------- flash attention over COMPACTED keys ----------------
// 256 threads (4 waves x 32q), grid 768 (3 blk/CU). K/V double-buffered with
// counted vmcnt(4) + raw barriers. Keys gathered to valid-only (~50%): tile
// count nt = ceil(cnt/64); final partial tile gated post-exp (so garbage
// pad-K rows cannot inject inf/NaN). No mask bias anywhere.
__global__ __launch_bounds__(256, 3) void attn_kernel(const u16* __restrict__ Q,
                                                      const u16* __restrict__ K,
                                                      const u16* __restrict__ Vt,
                                                      const int* __restrict__ cntg,
                                                      u16* __restrict__ Ctx) {
    __shared__ __align__(16) u16 lK[2][4096];
    __shared__ __align__(16) u16 lV[2][4096];   // [d][key]
    const int tid = threadIdx.x, lane = tid & 63, wave = tid >> 6;  // 4 waves
    const int quad = lane >> 4, lc = lane & 15;
    const int bh = blockIdx.x % (NB * HH);
    const int b = bh / HH, h = bh - b * HH;
    const int q0 = (blockIdx.x / (NB * HH)) * 128;
    const u16* Qg = Q + ((size_t)bh * SS + q0 + wave * 32) * HD;
    const u16* Kg = K + (size_t)bh * SS * HD;
    const u16* Vg = Vt + (size_t)bh * HD * SS;
    const int sw = lc & 7;
    const int cnt = cntg[b];
    const int nt = (cnt + 63) >> 6;

    // staging: 256 threads, 2 rounds cover 64 rows x 8 chunks of 16B
    const int srow = tid >> 3, scl = (tid & 7) ^ (srow & 7);
    const int srow2 = (256 + tid) >> 3, scl2 = (tid & 7) ^ (srow2 & 7);

    auto stage = [&](int bi, int j0) {
        gl_lds16(Kg + (size_t)(j0 + srow) * HD + scl * 8,   &lK[bi][(size_t)(wave * 64) * 8]);
        gl_lds16(Kg + (size_t)(j0 + srow2) * HD + scl2 * 8, &lK[bi][(size_t)(256 + wave * 64) * 8]);
        gl_lds16(Vg + (size_t)srow * SS + j0 + scl * 8,     &lV[bi][(size_t)(wave * 64) * 8]);
        gl_lds16(Vg + (size_t)srow2 * SS + j0 + scl2 * 8,   &lV[bi][(size_t)(256 + wave * 64) * 8]);
    };

    // Q fragments (B-operand): q = wave*32 + mi*16 + lc, k = k2*32 + quad*8 + j
    bf16x8 qf[2][2];
#pragma unroll
    for (int mi = 0; mi < 2; ++mi)
#pragma unroll
        for (int k2 = 0; k2 < 2; ++k2)
            qf[mi][k2] = *(const bf16x8*)(Qg + (size_t)(mi * 16 + lc) * HD + k2 * 32 + quad * 8);

    bf16x8 onesf;
#pragma unroll
    for (int i = 0; i < 8; ++i) onesf[i] = (__bf16)1.0f;

    f32x4 oacc[2][4] = {};
    f32x4 lsum[2] = {};

    stage(0, 0);
    for (int t = 0; t < nt; ++t) {
        const int cur = t & 1;
        if (t < nt - 1) {
            stage(cur ^ 1, (t + 1) * 64);
            __builtin_amdgcn_sched_barrier(0);
            asm volatile("s_waitcnt vmcnt(4)" ::: "memory");  // cur's 4 loads done; next 4 in flight
        } else {
            __builtin_amdgcn_sched_barrier(0);
            asm volatile("s_waitcnt vmcnt(0)" ::: "memory");
        }
        __builtin_amdgcn_sched_barrier(0);
        __builtin_amdgcn_s_barrier();
        __builtin_amdgcn_sched_barrier(0);

        const u16* bK = &lK[cur][0];
        const u16* bV = &lV[cur][0];

        // S^T = K Q^T: per-lane q = mi*16 + lc, key = ni*16 + quad*4 + r
        f32x4 sacc[2][4] = {};
        __builtin_amdgcn_s_setprio(1);
#pragma unroll
        for (int k2 = 0; k2 < 2; ++k2) {
            bf16x8 kf[4];
#pragma unroll
            for (int ni = 0; ni < 4; ++ni)
                kf[ni] = *(const bf16x8*)&bK[(ni * 16 + lc) * 64 + ((quad + k2 * 4) ^ sw) * 8];
#pragma unroll
            for (int ni = 0; ni < 4; ++ni) {
                sacc[0][ni] = __builtin_amdgcn_mfma_f32_16x16x32_bf16(kf[ni], qf[0][k2], sacc[0][ni], 0, 0, 0);
                sacc[1][ni] = __builtin_amdgcn_mfma_f32_16x16x32_bf16(kf[ni], qf[1][k2], sacc[1][ni], 0, 0, 0);
            }
        }
        __builtin_amdgcn_s_setprio(0);

        // p = exp2(s*log2e/8); gate pad keys of the last tile; pack to bf16x2
        const int kb_ = cnt - t * 64;
        const bool part = kb_ < 64;
        u32 pa[2][4], pb[2][4];
#pragma unroll
        for (int ni = 0; ni < 4; ++ni) {
#pragma unroll
            for (int mi = 0; mi < 2; ++mi) {
#pragma unroll
                for (int r = 0; r < 4; ++r) {
                    float e = __builtin_amdgcn_exp2f(sacc[mi][ni][r] * 0.180336880f);
                    if (part) e = (ni * 16 + quad * 4 + r < kb_) ? e : 0.0f;
                    sacc[mi][ni][r] = e;
                }
                pa[mi][ni] = __builtin_amdgcn_perm(fas(sacc[mi][ni][1]), fas(sacc[mi][ni][0]), 0x07060302);
                pb[mi][ni] = __builtin_amdgcn_perm(fas(sacc[mi][ni][3]), fas(sacc[mi][ni][2]), 0x07060302);
            }
        }

        // In-register S^T (C-layout) -> P (A-frag) transform (per mi, k2).
        bf16x8 pf[2][2];
#pragma unroll
        for (int mi = 0; mi < 2; ++mi)
#pragma unroll
            for (int k2 = 0; k2 < 2; ++k2) {
                u32 xa = pa[mi][2 * k2], ya = pa[mi][2 * k2 + 1];
                u32 xb = pb[mi][2 * k2], yb = pb[mi][2 * k2 + 1];
                asm("v_permlane32_swap_b32 %0, %1" : "+v"(xa), "+v"(ya));
                asm("v_permlane16_swap_b32 %0, %1" : "+v"(xa), "+v"(ya));
                asm("v_permlane32_swap_b32 %0, %1" : "+v"(xb), "+v"(yb));
                asm("v_permlane16_swap_b32 %0, %1" : "+v"(xb), "+v"(yb));
                u32x4 pw = { xa, xb, ya, yb };
                pf[mi][k2] = __builtin_bit_cast(bf16x8, pw);
            }

        // O += P V ; l += P * ones
        __builtin_amdgcn_s_setprio(1);
#pragma unroll
        for (int k2 = 0; k2 < 2; ++k2) {
            lsum[0] = __builtin_amdgcn_mfma_f32_16x16x32_bf16(pf[0][k2], onesf, lsum[0], 0, 0, 0);
            lsum[1] = __builtin_amdgcn_mfma_f32_16x16x32_bf16(pf[1][k2], onesf, lsum[1], 0, 0, 0);
#pragma unroll
            for (int ni = 0; ni < 4; ++ni) {
                bf16x8 vf = *(const bf16x8*)&bV[(ni * 16 + lc) * 64 + ((quad + k2 * 4) ^ sw) * 8];
                oacc[0][ni] = __builtin_amdgcn_mfma_f32_16x16x32_bf16(pf[0][k2], vf, oacc[0][ni], 0, 0, 0);
                oacc[1][ni] = __builtin_amdgcn_mfma_f32_16x16x32_bf16(pf[1][k2], vf, oacc[1][ni], 0, 0, 0);
            }
        }
        __builtin_amdgcn_s_setprio(0);

        __builtin_amdgcn_sched_barrier(0);
        __builtin_amdgcn_s_barrier();   // protect buf[cur^1] before next stage overwrites
    }

    // epilogue: normalize and store
#pragma unroll
    for (int mi = 0; mi < 2; ++mi)
#pragma unroll
        for (int r = 0; r < 4; ++r) {
            float inv = 1.0f / lsum[mi][r];
            int s = q0 + wave * 32 + mi * 16 + quad * 4 + r;
            size_t base = ((size_t)(b * SS + s)) * DD + h * HD;
#pragma unroll
            for (int ni = 0; ni < 4; ++ni)
                Ctx[base + ni * 16 + lc] = f2bf(oacc[mi][ni][r] * inv);
        }
}

// ---------------- LayerNorm over 768, one block per row ----------------
__global__ __launch_bounds__(256) void ln_kernel(const float* __restrict__ in,
                                                 const float* __restrict__ g,
                                                 const float* __restrict__ bb,
                                                 u16* __restrict__ out_bf,
                                                 float* __restrict__ out_f) {
    const int row = blockIdx.x, tid = threadIdx.x;
    const float* x = in + (size_t)row * DD;
    float v0 = x[tid], v1 = x[tid + 256], v2 = x[tid + 512];
    float s = v0 + v1 + v2;
    float q = v0 * v0 + v1 * v1 + v2 * v2;
#pragma unroll
    for (int o = 1; o < 64; o <<= 1) {
        s += __shfl_xor(s, o);
        q += __shfl_xor(q, o);
    }
    __shared__ float rs[4], rq[4];
    int wave = tid >> 6;
    if ((tid & 63) == 0) { rs[wave] = s; rq[wave] = q; }
    __syncthreads();
    s = rs[0] + rs[1] + rs[2] + rs[3];
    q = rq[0] + rq[1] + rq[2] + rq[3];
    float mu = s * (1.0f / DD);
    float var = q * (1.0f / DD) - mu * mu;
    float rstd = rsqrtf(var + 1e-5f);
#pragma unroll
    for (int j = 0; j < 3; ++j) {
        int col = tid + j * 256;
        float v = (j == 0 ? v0 : (j == 1 ? v1 : v2));
        float y = (v - mu) * rstd * g[col] + bb[col];
        if (out_bf) out_bf[(size_t)row * DD + col] = f2bf(y);
        if (out_f) out_f[(size_t)row * DD + col] = y;
    }
}

extern "C" void kernel_launch(void* const* d_in, const int* in_sizes, int n_in,
                              void* d_out, int out_size, void* d_ws, size_t ws_size,
                              hipStream_t stream) {
    const float* X    = (const float*)d_in[0];
    const int*   mask = (const int*)d_in[1];
    const float* Wq   = (const float*)d_in[2];
    const float* Wk   = (const float*)d_in[3];
    const float* Wv   = (const float*)d_in[4];
    const float* Wo   = (const float*)d_in[5];
    const float* W1   = (const float*)d_in[6];
    const float* W2   = (const float*)d_in[7];
    const float* ln_g = (const float*)d_in[8];
    const float* ln_b = (const float*)d_in[9];
    float* out = (float*)d_out;

    char* ws = (char*)d_ws;
    size_t off = 0;
    auto alloc = [&](size_t bytes) {
        void* p = ws + off;
        off += (bytes + 255) & ~(size_t)255;
        return p;
    };
    u16*   Xbf   = (u16*)alloc((size_t)ROWS * DD * 2);       // reused as Ctx
    u16*   Wqkvb = (u16*)alloc((size_t)3 * DD * DD * 2);
    u16*   Wob   = (u16*)alloc((size_t)DD * DD * 2);
    u16*   W1b   = (u16*)alloc((size_t)4 * DD * DD * 2);
    u16*   W2b   = (u16*)alloc((size_t)4 * DD * DD * 2);
    int*   cidx  = (int*)alloc((size_t)NB * SS * 4);
    int*   cnt   = (int*)alloc(256);
    u16*   Qb    = (u16*)alloc((size_t)ROWS * DD * 2);       // Qb..Vtb reused as Gb
    u16*   Kb    = (u16*)alloc((size_t)ROWS * DD * 2);
    u16*   Vb    = (u16*)alloc((size_t)ROWS * DD * 2);
    u16*   Vtb   = (u16*)alloc((size_t)ROWS * DD * 2);
    float* resid = (float*)alloc((size_t)ROWS * DD * 4);     // reused as h2
    u16*   n1b   = (u16*)alloc((size_t)ROWS * DD * 2);
    u16*   Gb    = Qb;          // 8192*3072*2 = 4 * (8192*768*2) = Qb..Vtb
    u16*   Ctxb  = Xbf;
    float* h2    = resid;

    // fused casts + valid-key scan (13056 + NB blocks)
    prep_kernel<<<dim3(13056 + NB), dim3(256), 0, stream>>>(
        X, Wq, Wk, Wv, Wo, W1, W2, mask,
        Xbf, Wqkvb, Wob, W1b, W2b, cidx, cnt);

    // QKV projection: [8192, 2304], XCD-slab 1D grid; K/V gather-compacted
    gemm_bt<0, 128><<<dim3((3 * DD / 128) * (ROWS / 128)), dim3(256), 0, stream>>>(
        Xbf, Wqkvb, ROWS, 3 * DD, DD, nullptr, nullptr, Qb, Kb, Vb, cidx);

    transpose_v<<<dim3(SS / 32, HD / 32, NB * HH), dim3(256), 0, stream>>>(Vb, Vtb, cnt);

    // 1D XCD-swizzled grid: id = qb*48 + bh; compacted keys
    attn_kernel<<<dim3((SS / 128) * (NB * HH)), dim3(256), 0, stream>>>(
        Qb, Kb, Vtb, cnt, Ctxb);

    // O projection + residual: resid = x + ctx @ Wo^T
    gemm_bt<2, 64><<<dim3((DD / 64) * (ROWS / 128)), dim3(256), 0, stream>>>(
        Ctxb, Wob, ROWS, DD, DD, resid, X, nullptr, nullptr, nullptr, nullptr);

    ln_kernel<<<dim3(ROWS), dim3(256), 0, stream>>>(resid, ln_g, ln_b, n1b, nullptr);

    // FFN1 + GELU(tanh-form): [8192, 3072] bf16
    gemm_bt<1, 128><<<dim3((4 * DD / 128) * (ROWS / 128)), dim3(256), 0, stream>>>(
        n1b, W1b, ROWS, 4 * DD, DD, Gb, nullptr, nullptr, nullptr, nullptr, nullptr);

    // FFN2 + residual: h2 = n1 + g @ W2^T
    gemm_bt<3, 64><<<dim3((DD / 64) * (ROWS / 128)), dim3(256), 0, stream>>>(
        Gb, W2b, ROWS, DD, 4 * DD, h2, n1b, nullptr, nullptr, nullptr, nullptr);

    ln_kernel<<<dim3(ROWS), dim3(256), 0, stream>>>(h2, ln_g, ln_b, nullptr, out);
}

// Round 6
// 340.379 us; speedup vs baseline: 1.0151x; 1.0151x over previous
//
#include <hip/hip_runtime.h>
#include <math.h>

typedef unsigned short u16;
typedef unsigned int u32;
typedef __bf16 bf16x8 __attribute__((ext_vector_type(8)));
typedef float f32x4 __attribute__((ext_vector_type(4)));
typedef u32 u32x4 __attribute__((ext_vector_type(4)));

#define NB 4
#define SS 2048
#define DD 768
#define HH 12
#define HD 64
#define ROWS (NB*SS)   // 8192

__device__ __forceinline__ u16 f2bf(float f) {
    union { float f; unsigned u; } v; v.f = f;
    unsigned r = v.u + 0x7fffu + ((v.u >> 16) & 1u);
    return (u16)(r >> 16);
}
__device__ __forceinline__ u32 fas(float f) { union { float f; u32 u; } v; v.f = f; return v.u; }

__device__ __forceinline__ void gl_lds16(const void* g, void* l) {
    __builtin_amdgcn_global_load_lds((__attribute__((address_space(1))) void*)(g),
                                     (__attribute__((address_space(3))) void*)(l),
                                     16, 0, 0);
}

// ---------------- fused prep: all f32->bf16 casts + valid-key scan ----------------
__global__ __launch_bounds__(256) void prep_kernel(
        const float* __restrict__ X, const float* __restrict__ Wq,
        const float* __restrict__ Wk, const float* __restrict__ Wv,
        const float* __restrict__ Wo, const float* __restrict__ W1,
        const float* __restrict__ W2, const int* __restrict__ mask,
        u16* __restrict__ Xb, u16* __restrict__ Wqkvb, u16* __restrict__ Wob,
        u16* __restrict__ W1b, u16* __restrict__ W2b,
        int* __restrict__ cidx, int* __restrict__ cnt) {
    const int blk = blockIdx.x, tid = threadIdx.x;
    const float* src; u16* dst; int idx;
    if (blk < 6144)       { src = X;  dst = Xb;               idx = blk * 1024 + tid * 4; }
    else if (blk < 6720)  { src = Wq; dst = Wqkvb;            idx = (blk - 6144) * 1024 + tid * 4; }
    else if (blk < 7296)  { src = Wk; dst = Wqkvb + DD * DD;  idx = (blk - 6720) * 1024 + tid * 4; }
    else if (blk < 7872)  { src = Wv; dst = Wqkvb + 2*DD*DD;  idx = (blk - 7296) * 1024 + tid * 4; }
    else if (blk < 8448)  { src = Wo; dst = Wob;              idx = (blk - 7872) * 1024 + tid * 4; }
    else if (blk < 10752) { src = W1; dst = W1b;              idx = (blk - 8448) * 1024 + tid * 4; }
    else if (blk < 13056) { src = W2; dst = W2b;              idx = (blk - 10752) * 1024 + tid * 4; }
    else {
        // scan block: b = blk - 13056
        const int b = blk - 13056;
        const int lane = tid & 63, wave = tid >> 6;
        const int base = b * SS + tid * 8;
        int4 m0 = *(const int4*)&mask[base];
        int4 m1 = *(const int4*)&mask[base + 4];
        int v[8] = { m0.x != 0, m0.y != 0, m0.z != 0, m0.w != 0,
                     m1.x != 0, m1.y != 0, m1.z != 0, m1.w != 0 };
        int own = 0;
#pragma unroll
        for (int i = 0; i < 8; ++i) own += v[i];
        int inc = own;
#pragma unroll
        for (int o = 1; o < 64; o <<= 1) {
            int n = __shfl_up(inc, o);
            if (lane >= o) inc += n;
        }
        __shared__ int wsum[4];
        if (lane == 63) wsum[wave] = inc;
        __syncthreads();
        int wbase = 0;
#pragma unroll
        for (int w = 0; w < 4; ++w) wbase += (w < wave) ? wsum[w] : 0;
        int pos = wbase + inc - own;   // exclusive prefix
        int o8[8];
#pragma unroll
        for (int i = 0; i < 8; ++i) { o8[i] = v[i] ? pos : -1; pos += v[i]; }
        *(int4*)&cidx[base]     = make_int4(o8[0], o8[1], o8[2], o8[3]);
        *(int4*)&cidx[base + 4] = make_int4(o8[4], o8[5], o8[6], o8[7]);
        if (tid == 255) cnt[b] = wbase + inc;
        return;
    }
    float4 v = *(const float4*)&src[idx];
    ushort4 o;
    o.x = f2bf(v.x); o.y = f2bf(v.y); o.z = f2bf(v.z); o.w = f2bf(v.w);
    *(ushort4*)&dst[idx] = o;
}

// ---------------- GEMM: C[M,N] = A[M,K] (bf16) * B[N,K]^T (bf16) ----------------
// r4 single-buffer structure (32 KB LDS, ~3 blk/CU). r5's 64KB dbuf regressed
// (occupancy 28.7->15.7%): keep this for QKV / O-proj / FFN2.
// EPI 0: scatter Q + gather-compact K/V | 2: +auxF f32 | 3: +auxB f32
template <int EPI, int BN>
__global__ __launch_bounds__(256) void gemm_bt(const u16* __restrict__ A,
                                               const u16* __restrict__ B,
                                               int M, int N, int K,
                                               void* __restrict__ out,
                                               const void* __restrict__ aux,
                                               u16* __restrict__ Qb,
                                               u16* __restrict__ Kb,
                                               u16* __restrict__ Vb,
                                               const int* __restrict__ cidx) {
    __shared__ __align__(16) u16 lA[128 * 64];
    __shared__ __align__(16) u16 lB[BN * 64];
    constexpr int MI = (BN == 128) ? 4 : 2;
    const int tid = threadIdx.x;
    const int lane = tid & 63, wave = tid >> 6;
    const int quad = lane >> 4, lc = lane & 15;
    const int xcd = blockIdx.x & 7, loc = blockIdx.x >> 3;
    const int mb = xcd * 8 + (loc & 7), nb = loc >> 3;   // M=8192 fixed: 64 m-blocks
    const int m0 = mb * 128, n0 = nb * BN;
    const int wrow = (BN == 128) ? (wave >> 1) * 64 : wave * 32;
    const int wcol = (BN == 128) ? (wave & 1) * 64 : 0;
    const int swz = lc & 7;

    f32x4 acc[MI][4] = {};

    for (int kb = 0; kb < K; kb += 64) {
        __syncthreads();
#pragma unroll
        for (int p0 = 0; p0 < 1024; p0 += 256) {
            int p = p0 + tid, row = p >> 3, cl = (p & 7) ^ (row & 7);
            gl_lds16(A + (size_t)(m0 + row) * K + kb + cl * 8, &lA[(size_t)(p0 + wave * 64) * 8]);
        }
#pragma unroll
        for (int p0 = 0; p0 < BN * 8; p0 += 256) {
            int p = p0 + tid, row = p >> 3, cl = (p & 7) ^ (row & 7);
            gl_lds16(B + (size_t)(n0 + row) * K + kb + cl * 8, &lB[(size_t)(p0 + wave * 64) * 8]);
        }
        __syncthreads();
#pragma unroll
        for (int k2 = 0; k2 < 2; ++k2) {
            bf16x8 af[MI], bfr[4];
#pragma unroll
            for (int t = 0; t < MI; ++t)
                af[t] = *(const bf16x8*)&lA[(wrow + t * 16 + lc) * 64 + ((quad + k2 * 4) ^ swz) * 8];
#pragma unroll
            for (int t = 0; t < 4; ++t)
                bfr[t] = *(const bf16x8*)&lB[(wcol + t * 16 + lc) * 64 + ((quad + k2 * 4) ^ swz) * 8];
#pragma unroll
            for (int mi = 0; mi < MI; ++mi)
#pragma unroll
                for (int ni = 0; ni < 4; ++ni)
                    acc[mi][ni] = __builtin_amdgcn_mfma_f32_16x16x32_bf16(af[mi], bfr[ni],
                                                                         acc[mi][ni], 0, 0, 0);
        }
    }

#pragma unroll
    for (int mi = 0; mi < MI; ++mi) {
        int csa[4];
        if constexpr (EPI == 0) {
            int mbase = m0 + wrow + mi * 16 + quad * 4;
            int4 cs4 = *(const int4*)&cidx[(mbase >> 11) * SS + (mbase & 2047)];
            csa[0] = cs4.x; csa[1] = cs4.y; csa[2] = cs4.z; csa[3] = cs4.w;
        }
#pragma unroll
        for (int r = 0; r < 4; ++r) {
            int m = m0 + wrow + mi * 16 + quad * 4 + r;
#pragma unroll
            for (int ni = 0; ni < 4; ++ni) {
                int n = n0 + wcol + ni * 16 + lc;
                float v = acc[mi][ni][r];
                if constexpr (EPI == 0) {
                    int b = m >> 11, s = m & 2047;
                    int which = n / DD, rem = n - which * DD;
                    int h = rem >> 6, d = rem & 63;
                    u16* dst = which == 0 ? Qb : (which == 1 ? Kb : Vb);
                    int sidx = which == 0 ? s : csa[r];   // K/V: gather-compact
                    if (sidx >= 0)
                        dst[((((size_t)b * HH + h) * SS + sidx) << 6) + d] = f2bf(v);
                } else if constexpr (EPI == 1) {
                    float u = v * fmaf(v * v, 0.035677408f, 0.7978845608f);
                    float e = __builtin_amdgcn_exp2f(u * 2.885390082f);
                    float g = v - v * __builtin_amdgcn_rcpf(e + 1.0f);
                    ((u16*)out)[(size_t)m * N + n] = f2bf(g);
                } else if constexpr (EPI == 2) {
                    ((float*)out)[(size_t)m * N + n] =
                        v + ((const float*)aux)[(size_t)m * N + n];
                } else {
                    ((float*)out)[(size_t)m * N + n] =
                        v + (float)(((const __bf16*)aux)[(size_t)m * N + n]);
                }
            }
        }
    }
}

// ---------------- 8-phase 256x256 GEMM (m201 template) for FFN1 ----------------
// C[M,N] = GELU(A[M,K] * B[N,K]^T), bf16. 512 thr (8 waves = 2Mx4N), BK=64,
// 128 KB dbuf LDS (1 blk/CU). Per K-tile: 4 phases, each {ds_read subtile ||
// prefetch issue -> barrier -> lgkmcnt(0) -> setprio 16xMFMA -> barrier}.
// Prefetch front-loaded (A rounds @ph0, B rounds @ph1) so the per-tile
// vmcnt(0) at phase 3 has 2-3 phases of HBM slack (T3+T4+T5).
template <int EPI>
__global__ __launch_bounds__(512, 2) void gemm256_bt(const u16* __restrict__ A,
                                                     const u16* __restrict__ B,
                                                     int M, int N, int K,
                                                     void* __restrict__ out) {
    __shared__ __align__(16) u16 lA[2][256 * 64];
    __shared__ __align__(16) u16 lB[2][256 * 64];
    const int tid = threadIdx.x;
    const int lane = tid & 63, wave = tid >> 6;          // 8 waves
    const int quad = lane >> 4, lc = lane & 15;
    const int xcd = blockIdx.x & 7, loc = blockIdx.x >> 3;
    const int mpx = (M >> 8) >> 3;                        // m-blocks per xcd (4)
    const int mb = xcd * mpx + (loc % mpx), nb = loc / mpx;
    const int m0 = mb * 256, n0 = nb * 256;
    const int wrow = (wave >> 2) * 128;                   // 2 row-groups of 128
    const int wcol = (wave & 3) * 64;                     // 4 col-groups of 64
    const int swz = lc & 7;

    // staging round r (4 A-rounds + 4 B-rounds per K-tile of 256x64):
    // p = r*512 + tid; row = p>>3 in [0,256); chunk-XOR swizzle as gemm_bt.
    auto stageA = [&](int bi, int kb, int r) {
        int p = r * 512 + tid, row = p >> 3, cl = (p & 7) ^ (row & 7);
        gl_lds16(A + (size_t)(m0 + row) * K + kb + cl * 8,
                 &lA[bi][(size_t)(r * 512 + wave * 64) * 8]);
    };
    auto stageB = [&](int bi, int kb, int r) {
        int p = r * 512 + tid, row = p >> 3, cl = (p & 7) ^ (row & 7);
        gl_lds16(B + (size_t)(n0 + row) * K + kb + cl * 8,
                 &lB[bi][(size_t)(r * 512 + wave * 64) * 8]);
    };

    f32x4 acc[8][4] = {};
    const int KT = K >> 6;

    // prologue: stage K-tile 0 into buf 0
#pragma unroll
    for (int r = 0; r < 4; ++r) stageA(0, 0, r);
#pragma unroll
    for (int r = 0; r < 4; ++r) stageB(0, 0, r);
    asm volatile("s_waitcnt vmcnt(0)" ::: "memory");
    __builtin_amdgcn_sched_barrier(0);
    __builtin_amdgcn_s_barrier();
    __builtin_amdgcn_sched_barrier(0);

    for (int t = 0; t < KT; ++t) {
        const int cur = t & 1;
        const u16* bA = &lA[cur][0];
        const u16* bB = &lB[cur][0];
        const bool pf = (t + 1) < KT;
        const int kb1 = (t + 1) << 6;
        bf16x8 af[4], bf[4];

        // ---- phase 0: k2=0, mi 0..3 (+B frags); prefetch next A rounds ----
#pragma unroll
        for (int i = 0; i < 4; ++i)
            af[i] = *(const bf16x8*)&bA[(wrow + i * 16 + lc) * 64 + (quad ^ swz) * 8];
#pragma unroll
        for (int j = 0; j < 4; ++j)
            bf[j] = *(const bf16x8*)&bB[(wcol + j * 16 + lc) * 64 + (quad ^ swz) * 8];
        if (pf) { stageA(cur ^ 1, kb1, 0); stageA(cur ^ 1, kb1, 1);
                  stageA(cur ^ 1, kb1, 2); stageA(cur ^ 1, kb1, 3); }
        __builtin_amdgcn_sched_barrier(0);
        __builtin_amdgcn_s_barrier();
        asm volatile("s_waitcnt lgkmcnt(0)" ::: "memory");
        __builtin_amdgcn_sched_barrier(0);
        __builtin_amdgcn_s_setprio(1);
#pragma unroll
        for (int i = 0; i < 4; ++i)
#pragma unroll
            for (int j = 0; j < 4; ++j)
                acc[i][j] = __builtin_amdgcn_mfma_f32_16x16x32_bf16(af[i], bf[j], acc[i][j], 0, 0, 0);
        __builtin_amdgcn_s_setprio(0);
        __builtin_amdgcn_sched_barrier(0);
        __builtin_amdgcn_s_barrier();
        __builtin_amdgcn_sched_barrier(0);

        // ---- phase 1: k2=0, mi 4..7; prefetch next B rounds ----
#pragma unroll
        for (int i = 0; i < 4; ++i)
            af[i] = *(const bf16x8*)&bA[(wrow + 64 + i * 16 + lc) * 64 + (quad ^ swz) * 8];
        if (pf) { stageB(cur ^ 1, kb1, 0); stageB(cur ^ 1, kb1, 1);
                  stageB(cur ^ 1, kb1, 2); stageB(cur ^ 1, kb1, 3); }
        __builtin_amdgcn_sched_barrier(0);
        __builtin_amdgcn_s_barrier();
        asm volatile("s_waitcnt lgkmcnt(0)" ::: "memory");
        __builtin_amdgcn_sched_barrier(0);
        __builtin_amdgcn_s_setprio(1);
#pragma unroll
        for (int i = 0; i < 4; ++i)
#pragma unroll
            for (int j = 0; j < 4; ++j)
                acc[4 + i][j] = __builtin_amdgcn_mfma_f32_16x16x32_bf16(af[i], bf[j], acc[4 + i][j], 0, 0, 0);
        __builtin_amdgcn_s_setprio(0);
        __builtin_amdgcn_sched_barrier(0);
        __builtin_amdgcn_s_barrier();
        __builtin_amdgcn_sched_barrier(0);

        // ---- phase 2: k2=1, mi 0..3 ----
#pragma unroll
        for (int i = 0; i < 4; ++i)
            af[i] = *(const bf16x8*)&bA[(wrow + i * 16 + lc) * 64 + ((quad + 4) ^ swz) * 8];
#pragma unroll
        for (int j = 0; j < 4; ++j)
            bf[j] = *(const bf16x8*)&bB[(wcol + j * 16 + lc) * 64 + ((quad + 4) ^ swz) * 8];
        __builtin_amdgcn_sched_barrier(0);
        __builtin_amdgcn_s_barrier();
        asm volatile("s_waitcnt lgkmcnt(0)" ::: "memory");
        __builtin_amdgcn_sched_barrier(0);
        __builtin_amdgcn_s_setprio(1);
#pragma unroll
        for (int i = 0; i < 4; ++i)
#pragma unroll
            for (int j = 0; j < 4; ++j)
                acc[i][j] = __builtin_amdgcn_mfma_f32_16x16x32_bf16(af[i], bf[j], acc[i][j], 0, 0, 0);
        __builtin_amdgcn_s_setprio(0);
        __builtin_amdgcn_sched_barrier(0);
        __builtin_amdgcn_s_barrier();
        __builtin_amdgcn_sched_barrier(0);

        // ---- phase 3: k2=1, mi 4..7; per-tile vmcnt(0) with 2-3 phase slack ----
#pragma unroll
        for (int i = 0; i < 4; ++i)
            af[i] = *(const bf16x8*)&bA[(wrow + 64 + i * 16 + lc) * 64 + ((quad + 4) ^ swz) * 8];
        __builtin_amdgcn_sched_barrier(0);
        __builtin_amdgcn_s_barrier();
        asm volatile("s_waitcnt lgkmcnt(0)" ::: "memory");
        __builtin_amdgcn_sched_barrier(0);
        __builtin_amdgcn_s_setprio(1);
#pragma unroll
        for (int i = 0; i < 4; ++i)
#pragma unroll
            for (int j = 0; j < 4; ++j)
                acc[4 + i][j] = __builtin_amdgcn_mfma_f32_16x16x32_bf16(af[i], bf[j], acc[4 + i][j], 0, 0, 0);
        __builtin_amdgcn_s_setprio(0);
        if (pf) asm volatile("s_waitcnt vmcnt(0)" ::: "memory");   // next tile fully landed
        __builtin_amdgcn_sched_barrier(0);
        __builtin_amdgcn_s_barrier();
        __builtin_amdgcn_sched_barrier(0);
    }

    // epilogue (EPI==1: tanh-GELU -> bf16)
#pragma unroll
    for (int mi = 0; mi < 8; ++mi) {
        int mrow = m0 + wrow + (mi >> 2) * 64 + (mi & 3) * 16 + quad * 4;
#pragma unroll
        for (int r = 0; r < 4; ++r) {
            int m = mrow + r;
#pragma unroll
            for (int ni = 0; ni < 4; ++ni) {
                int n = n0 + wcol + ni * 16 + lc;
                float v = acc[mi][ni][r];
                float u = v * fmaf(v * v, 0.035677408f, 0.7978845608f);
                float e = __builtin_amdgcn_exp2f(u * 2.885390082f);
                float g = v - v * __builtin_amdgcn_rcpf(e + 1.0f);
                ((u16*)out)[(size_t)m * N + n] = f2bf(g);
            }
        }
    }
}

// ---------------- V transpose: compact [B,H,S,D] -> [B,H,D,S], zero-pad to 64 ----------------
__global__ __launch_bounds__(256) void transpose_v(const u16* __restrict__ V,
                                                   u16* __restrict__ Vt,
                                                   const int* __restrict__ cnt) {
    __shared__ u16 t[32][33];
    int bh = blockIdx.z;
    int c = cnt[bh / HH];
    int cr = (c + 63) & ~63;
    int s0 = blockIdx.x * 32, d0 = blockIdx.y * 32;
    if (s0 >= cr) return;
    const u16* vb = V + (size_t)bh * SS * HD;
    u16* vtb = Vt + (size_t)bh * HD * SS;
    int tx = threadIdx.x & 31, ty = threadIdx.x >> 5;
#pragma unroll
    for (int i = 0; i < 32; i += 8) {
        int s = s0 + ty + i;
        t[ty + i][tx] = (s < c) ? vb[(size_t)s * HD + d0 + tx] : (u16)0;
    }
    __syncthreads();
#pragma unroll
    for (int i = 0; i < 32; i += 8) vtb[(size_t)(d0 + ty + i) * SS + s0 + tx] = t[tx][ty + i];
}

// ---------------- flash attention over COMPACTED keys ----------------
__global__ __launch_bounds__(256, 3) void attn_kernel(const u16* __restrict__ Q,
                                                      const u16* __restrict__ K,
                                                      const u16* __restrict__ Vt,
                                                      const int* __restrict__ cntg,
                                                      u16* __restrict__ Ctx) {
    __shared__ __align__(16) u16 lK[2][4096];
    __shared__ __align__(16) u16 lV[2][4096];   // [d][key]
    const int tid = threadIdx.x, lane = tid & 63, wave = tid >> 6;  // 4 waves
    const int quad = lane >> 4, lc = lane & 15;
    const int bh = blockIdx.x % (NB * HH);
    const int b = bh / HH, h = bh - b * HH;
    const int q0 = (blockIdx.x / (NB * HH)) * 128;
    const u16* Qg = Q + ((size_t)bh * SS + q0 + wave * 32) * HD;
    const u16* Kg = K + (size_t)bh * SS * HD;
    const u16* Vg = Vt + (size_t)bh * HD * SS;
    const int sw = lc & 7;
    const int cnt = cntg[b];
    const int nt = (cnt + 63) >> 6;

    const int srow = tid >> 3, scl = (tid & 7) ^ (srow & 7);
    const int srow2 = (256 + tid) >> 3, scl2 = (tid & 7) ^ (srow2 & 7);

    auto stage = [&](int bi, int j0) {
        gl_lds16(Kg + (size_t)(j0 + srow) * HD + scl * 8,   &lK[bi][(size_t)(wave * 64) * 8]);
        gl_lds16(Kg + (size_t)(j0 + srow2) * HD + scl2 * 8, &lK[bi][(size_t)(256 + wave * 64) * 8]);
        gl_lds16(Vg + (size_t)srow * SS + j0 + scl * 8,     &lV[bi][(size_t)(wave * 64) * 8]);
        gl_lds16(Vg + (size_t)srow2 * SS + j0 + scl2 * 8,   &lV[bi][(size_t)(256 + wave * 64) * 8]);
    };

    bf16x8 qf[2][2];
#pragma unroll
    for (int mi = 0; mi < 2; ++mi)
#pragma unroll
        for (int k2 = 0; k2 < 2; ++k2)
            qf[mi][k2] = *(const bf16x8*)(Qg + (size_t)(mi * 16 + lc) * HD + k2 * 32 + quad * 8);

    bf16x8 onesf;
#pragma unroll
    for (int i = 0; i < 8; ++i) onesf[i] = (__bf16)1.0f;

    f32x4 oacc[2][4] = {};
    f32x4 lsum[2] = {};

    stage(0, 0);
    for (int t = 0; t < nt; ++t) {
        const int cur = t & 1;
        if (t < nt - 1) {
            stage(cur ^ 1, (t + 1) * 64);
            __builtin_amdgcn_sched_barrier(0);
            asm volatile("s_waitcnt vmcnt(4)" ::: "memory");
        } else {
            __builtin_amdgcn_sched_barrier(0);
            asm volatile("s_waitcnt vmcnt(0)" ::: "memory");
        }
        __builtin_amdgcn_sched_barrier(0);
        __builtin_amdgcn_s_barrier();
        __builtin_amdgcn_sched_barrier(0);

        const u16* bK = &lK[cur][0];
        const u16* bV = &lV[cur][0];

        f32x4 sacc[2][4] = {};
        __builtin_amdgcn_s_setprio(1);
#pragma unroll
        for (int k2 = 0; k2 < 2; ++k2) {
            bf16x8 kf[4];
#pragma unroll
            for (int ni = 0; ni < 4; ++ni)
                kf[ni] = *(const bf16x8*)&bK[(ni * 16 + lc) * 64 + ((quad + k2 * 4) ^ sw) * 8];
#pragma unroll
            for (int ni = 0; ni < 4; ++ni) {
                sacc[0][ni] = __builtin_amdgcn_mfma_f32_16x16x32_bf16(kf[ni], qf[0][k2], sacc[0][ni], 0, 0, 0);
                sacc[1][ni] = __builtin_amdgcn_mfma_f32_16x16x32_bf16(kf[ni], qf[1][k2], sacc[1][ni], 0, 0, 0);
            }
        }
        __builtin_amdgcn_s_setprio(0);

        const int kb_ = cnt - t * 64;
        const bool part = kb_ < 64;
        u32 pa[2][4], pb[2][4];
#pragma unroll
        for (int ni = 0; ni < 4; ++ni) {
#pragma unroll
            for (int mi = 0; mi < 2; ++mi) {
#pragma unroll
                for (int r = 0; r < 4; ++r) {
                    float e = __builtin_amdgcn_exp2f(sacc[mi][ni][r] * 0.180336880f);
                    if (part) e = (ni * 16 + quad * 4 + r < kb_) ? e : 0.0f;
                    sacc[mi][ni][r] = e;
                }
                pa[mi][ni] = __builtin_amdgcn_perm(fas(sacc[mi][ni][1]), fas(sacc[mi][ni][0]), 0x07060302);
                pb[mi][ni] = __builtin_amdgcn_perm(fas(sacc[mi][ni][3]), fas(sacc[mi][ni][2]), 0x07060302);
            }
        }

        bf16x8 pf[2][2];
#pragma unroll
        for (int mi = 0; mi < 2; ++mi)
#pragma unroll
            for (int k2 = 0; k2 < 2; ++k2) {
                u32 xa = pa[mi][2 * k2], ya = pa[mi][2 * k2 + 1];
                u32 xb = pb[mi][2 * k2], yb = pb[mi][2 * k2 + 1];
                asm("v_permlane32_swap_b32 %0, %1" : "+v"(xa), "+v"(ya));
                asm("v_permlane16_swap_b32 %0, %1" : "+v"(xa), "+v"(ya));
                asm("v_permlane32_swap_b32 %0, %1" : "+v"(xb), "+v"(yb));
                asm("v_permlane16_swap_b32 %0, %1" : "+v"(xb), "+v"(yb));
                u32x4 pw = { xa, xb, ya, yb };
                pf[mi][k2] = __builtin_bit_cast(bf16x8, pw);
            }

        __builtin_amdgcn_s_setprio(1);
#pragma unroll
        for (int k2 = 0; k2 < 2; ++k2) {
            lsum[0] = __builtin_amdgcn_mfma_f32_16x16x32_bf16(pf[0][k2], onesf, lsum[0], 0, 0, 0);
            lsum[1] = __builtin_amdgcn_mfma_f32_16x16x32_bf16(pf[1][k2], onesf, lsum[1], 0, 0, 0);
#pragma unroll
            for (int ni = 0; ni < 4; ++ni) {
                bf16x8 vf = *(const bf16x8*)&bV[(ni * 16 + lc) * 64 + ((quad + k2 * 4) ^ sw) * 8];
                oacc[0][ni] = __builtin_amdgcn_mfma_f32_16x16x32_bf16(pf[0][k2], vf, oacc[0][ni], 0, 0, 0);
                oacc[1][ni] = __builtin_amdgcn_mfma_f32_16x16x32_bf16(pf[1][k2], vf, oacc[1][ni], 0, 0, 0);
            }
        }
        __builtin_amdgcn_s_setprio(0);

        __builtin_amdgcn_sched_barrier(0);
        __builtin_amdgcn_s_barrier();
    }

#pragma unroll
    for (int mi = 0; mi < 2; ++mi)
#pragma unroll
        for (int r = 0; r < 4; ++r) {
            float inv = 1.0f / lsum[mi][r];
            int s = q0 + wave * 32 + mi * 16 + quad * 4 + r;
            size_t base = ((size_t)(b * SS + s)) * DD + h * HD;
#pragma unroll
            for (int ni = 0; ni < 4; ++ni)
                Ctx[base + ni * 16 + lc] = f2bf(oacc[mi][ni][r] * inv);
        }
}

// ---------------- LayerNorm over 768, one block per row ----------------
__global__ __launch_bounds__(256) void ln_kernel(const float* __restrict__ in,
                                                 const float* __restrict__ g,
                                                 const float* __restrict__ bb,
                                                 u16* __restrict__ out_bf,
                                                 float* __restrict__ out_f) {
    const int row = blockIdx.x, tid = threadIdx.x;
    const float* x = in + (size_t)row * DD;
    float v0 = x[tid], v1 = x[tid + 256], v2 = x[tid + 512];
    float s = v0 + v1 + v2;
    float q = v0 * v0 + v1 * v1 + v2 * v2;
#pragma unroll
    for (int o = 1; o < 64; o <<= 1) {
        s += __shfl_xor(s, o);
        q += __shfl_xor(q, o);
    }
    __shared__ float rs[4], rq[4];
    int wave = tid >> 6;
    if ((tid & 63) == 0) { rs[wave] = s; rq[wave] = q; }
    __syncthreads();
    s = rs[0] + rs[1] + rs[2] + rs[3];
    q = rq[0] + rq[1] + rq[2] + rq[3];
    float mu = s * (1.0f / DD);
    float var = q * (1.0f / DD) - mu * mu;
    float rstd = rsqrtf(var + 1e-5f);
#pragma unroll
    for (int j = 0; j < 3; ++j) {
        int col = tid + j * 256;
        float v = (j == 0 ? v0 : (j == 1 ? v1 : v2));
        float y = (v - mu) * rstd * g[col] + bb[col];
        if (out_bf) out_bf[(size_t)row * DD + col] = f2bf(y);
        if (out_f) out_f[(size_t)row * DD + col] = y;
    }
}

extern "C" void kernel_launch(void* const* d_in, const int* in_sizes, int n_in,
                              void* d_out, int out_size, void* d_ws, size_t ws_size,
                              hipStream_t stream) {
    const float* X    = (const float*)d_in[0];
    const int*   mask = (const int*)d_in[1];
    const float* Wq   = (const float*)d_in[2];
    const float* Wk   = (const float*)d_in[3];
    const float* Wv   = (const float*)d_in[4];
    const float* Wo   = (const float*)d_in[5];
    const float* W1   = (const float*)d_in[6];
    const float* W2   = (const float*)d_in[7];
    const float* ln_g = (const float*)d_in[8];
    const float* ln_b = (const float*)d_in[9];
    float* out = (float*)d_out;

    char* ws = (char*)d_ws;
    size_t off = 0;
    auto alloc = [&](size_t bytes) {
        void* p = ws + off;
        off += (bytes + 255) & ~(size_t)255;
        return p;
    };
    u16*   Xbf   = (u16*)alloc((size_t)ROWS * DD * 2);       // reused as Ctx
    u16*   Wqkvb = (u16*)alloc((size_t)3 * DD * DD * 2);
    u16*   Wob   = (u16*)alloc((size_t)DD * DD * 2);
    u16*   W1b   = (u16*)alloc((size_t)4 * DD * DD * 2);
    u16*   W2b   = (u16*)alloc((size_t)4 * DD * DD * 2);
    int*   cidx  = (int*)alloc((size_t)NB * SS * 4);
    int*   cnt   = (int*)alloc(256);
    u16*   Qb    = (u16*)alloc((size_t)ROWS * DD * 2);       // Qb..Vtb reused as Gb
    u16*   Kb    = (u16*)alloc((size_t)ROWS * DD * 2);
    u16*   Vb    = (u16*)alloc((size_t)ROWS * DD * 2);
    u16*   Vtb   = (u16*)alloc((size_t)ROWS * DD * 2);
    float* resid = (float*)alloc((size_t)ROWS * DD * 4);     // reused as h2
    u16*   n1b   = (u16*)alloc((size_t)ROWS * DD * 2);
    u16*   Gb    = Qb;          // 8192*3072*2 = 4 * (8192*768*2) = Qb..Vtb
    u16*   Ctxb  = Xbf;
    float* h2    = resid;

    // fused casts + valid-key scan (13056 + NB blocks)
    prep_kernel<<<dim3(13056 + NB), dim3(256), 0, stream>>>(
        X, Wq, Wk, Wv, Wo, W1, W2, mask,
        Xbf, Wqkvb, Wob, W1b, W2b, cidx, cnt);

    // QKV projection: [8192, 2304], XCD-slab 1D grid; K/V gather-compacted
    gemm_bt<0, 128><<<dim3((3 * DD / 128) * (ROWS / 128)), dim3(256), 0, stream>>>(
        Xbf, Wqkvb, ROWS, 3 * DD, DD, nullptr, nullptr, Qb, Kb, Vb, cidx);

    transpose_v<<<dim3(SS / 32, HD / 32, NB * HH), dim3(256), 0, stream>>>(Vb, Vtb, cnt);

    // 1D XCD-swizzled grid: id = qb*48 + bh; compacted keys
    attn_kernel<<<dim3((SS / 128) * (NB * HH)), dim3(256), 0, stream>>>(
        Qb, Kb, Vtb, cnt, Ctxb);

    // O projection + residual: resid = x + ctx @ Wo^T
    gemm_bt<2, 64><<<dim3((DD / 64) * (ROWS / 128)), dim3(256), 0, stream>>>(
        Ctxb, Wob, ROWS, DD, DD, resid, X, nullptr, nullptr, nullptr, nullptr);

    ln_kernel<<<dim3(ROWS), dim3(256), 0, stream>>>(resid, ln_g, ln_b, n1b, nullptr);

    // FFN1 + GELU: [8192, 3072] bf16 -- 8-phase 256^2 kernel (384 blocks, 512 thr)
    gemm256_bt<1><<<dim3((ROWS / 256) * (4 * DD / 256)), dim3(512), 0, stream>>>(
        n1b, W1b, ROWS, 4 * DD, DD, Gb);

    // FFN2 + residual: h2 = n1 + g @ W2^T
    gemm_bt<3, 64><<<dim3((DD / 64) * (ROWS / 128)), dim3(256), 0, stream>>>(
        Gb, W2b, ROWS, DD, 4 * DD, h2, n1b, nullptr, nullptr, nullptr, nullptr);

    ln_kernel<<<dim3(ROWS), dim3(256), 0, stream>>>(h2, ln_g, ln_b, nullptr, out);
}

// Round 8
// 332.277 us; speedup vs baseline: 1.0398x; 1.0244x over previous
//
#include <hip/hip_runtime.h>
#include <math.h>

typedef unsigned short u16;
typedef unsigned int u32;
typedef __bf16 bf16x8 __attribute__((ext_vector_type(8)));
typedef float f32x4 __attribute__((ext_vector_type(4)));
typedef u32 u32x4 __attribute__((ext_vector_type(4)));

#define NB 4
#define SS 2048
#define DD 768
#define HH 12
#define HD 64
#define ROWS (NB*SS)   // 8192

__device__ __forceinline__ u16 f2bf(float f) {
    union { float f; unsigned u; } v; v.f = f;
    unsigned r = v.u + 0x7fffu + ((v.u >> 16) & 1u);
    return (u16)(r >> 16);
}
__device__ __forceinline__ u32 fas(float f) { union { float f; u32 u; } v; v.f = f; return v.u; }

__device__ __forceinline__ void gl_lds16(const void* g, void* l) {
    __builtin_amdgcn_global_load_lds((__attribute__((address_space(1))) void*)(g),
                                     (__attribute__((address_space(3))) void*)(l),
                                     16, 0, 0);
}

// ---------------- fused prep: all f32->bf16 casts + valid-key scan ----------------
__global__ __launch_bounds__(256) void prep_kernel(
        const float* __restrict__ X, const float* __restrict__ Wq,
        const float* __restrict__ Wk, const float* __restrict__ Wv,
        const float* __restrict__ Wo, const float* __restrict__ W1,
        const float* __restrict__ W2, const int* __restrict__ mask,
        u16* __restrict__ Xb, u16* __restrict__ Wqkvb, u16* __restrict__ Wob,
        u16* __restrict__ W1b, u16* __restrict__ W2b,
        int* __restrict__ cidx, int* __restrict__ cnt) {
    const int blk = blockIdx.x, tid = threadIdx.x;
    const float* src; u16* dst; int idx;
    if (blk < 6144)       { src = X;  dst = Xb;               idx = blk * 1024 + tid * 4; }
    else if (blk < 6720)  { src = Wq; dst = Wqkvb;            idx = (blk - 6144) * 1024 + tid * 4; }
    else if (blk < 7296)  { src = Wk; dst = Wqkvb + DD * DD;  idx = (blk - 6720) * 1024 + tid * 4; }
    else if (blk < 7872)  { src = Wv; dst = Wqkvb + 2*DD*DD;  idx = (blk - 7296) * 1024 + tid * 4; }
    else if (blk < 8448)  { src = Wo; dst = Wob;              idx = (blk - 7872) * 1024 + tid * 4; }
    else if (blk < 10752) { src = W1; dst = W1b;              idx = (blk - 8448) * 1024 + tid * 4; }
    else if (blk < 13056) { src = W2; dst = W2b;              idx = (blk - 10752) * 1024 + tid * 4; }
    else {
        // scan block: b = blk - 13056
        const int b = blk - 13056;
        const int lane = tid & 63, wave = tid >> 6;
        const int base = b * SS + tid * 8;
        int4 m0 = *(const int4*)&mask[base];
        int4 m1 = *(const int4*)&mask[base + 4];
        int v[8] = { m0.x != 0, m0.y != 0, m0.z != 0, m0.w != 0,
                     m1.x != 0, m1.y != 0, m1.z != 0, m1.w != 0 };
        int own = 0;
#pragma unroll
        for (int i = 0; i < 8; ++i) own += v[i];
        int inc = own;
#pragma unroll
        for (int o = 1; o < 64; o <<= 1) {
            int n = __shfl_up(inc, o);
            if (lane >= o) inc += n;
        }
        __shared__ int wsum[4];
        if (lane == 63) wsum[wave] = inc;
        __syncthreads();
        int wbase = 0;
#pragma unroll
        for (int w = 0; w < 4; ++w) wbase += (w < wave) ? wsum[w] : 0;
        int pos = wbase + inc - own;   // exclusive prefix
        int o8[8];
#pragma unroll
        for (int i = 0; i < 8; ++i) { o8[i] = v[i] ? pos : -1; pos += v[i]; }
        *(int4*)&cidx[base]     = make_int4(o8[0], o8[1], o8[2], o8[3]);
        *(int4*)&cidx[base + 4] = make_int4(o8[4], o8[5], o8[6], o8[7]);
        if (tid == 255) cnt[b] = wbase + inc;
        return;
    }
    float4 v = *(const float4*)&src[idx];
    ushort4 o;
    o.x = f2bf(v.x); o.y = f2bf(v.y); o.z = f2bf(v.z); o.w = f2bf(v.w);
    *(ushort4*)&dst[idx] = o;
}

// ---------------- GEMM: C[M,N] = A[M,K] (bf16) * B[N,K]^T (bf16) ----------------
// r4 single-buffer structure (proven 337.3 us). BK template param: BK=128
// stacks two 64-col sub-tiles per staging round, halving the per-K-tile
// vmcnt(0)+barrier drains while keeping LDS <= 48 KB (3 blk/CU). Used for
// the BN=64 GEMMs (O-proj K=768, FFN2 K=3072). BN=128 stays BK=64 (64 KB
// would drop occupancy -- r5/m132 regression).
// EPI 0: scatter Q + gather-compact K/V | 1: tanh-GELU bf16 | 2: +auxF f32 | 3: +auxB f32
template <int EPI, int BN, int BK>
__global__ __launch_bounds__(256) void gemm_bt(const u16* __restrict__ A,
                                               const u16* __restrict__ B,
                                               int M, int N, int K,
                                               void* __restrict__ out,
                                               const void* __restrict__ aux,
                                               u16* __restrict__ Qb,
                                               u16* __restrict__ Kb,
                                               u16* __restrict__ Vb,
                                               const int* __restrict__ cidx) {
    constexpr int NH = BK / 64;          // 64-col sub-tiles per K-tile
    __shared__ __align__(16) u16 lA[NH][128 * 64];
    __shared__ __align__(16) u16 lB[NH][BN * 64];
    constexpr int MI = (BN == 128) ? 4 : 2;
    const int tid = threadIdx.x;
    const int lane = tid & 63, wave = tid >> 6;
    const int quad = lane >> 4, lc = lane & 15;
    const int xcd = blockIdx.x & 7, loc = blockIdx.x >> 3;
    const int mb = xcd * 8 + (loc & 7), nb = loc >> 3;   // M=8192 fixed: 64 m-blocks
    const int m0 = mb * 128, n0 = nb * BN;
    const int wrow = (BN == 128) ? (wave >> 1) * 64 : wave * 32;
    const int wcol = (BN == 128) ? (wave & 1) * 64 : 0;
    const int swz = lc & 7;

    f32x4 acc[MI][4] = {};

    for (int kb = 0; kb < K; kb += BK) {
        __syncthreads();
#pragma unroll
        for (int h = 0; h < NH; ++h) {
#pragma unroll
            for (int p0 = 0; p0 < 1024; p0 += 256) {
                int p = p0 + tid, row = p >> 3, cl = (p & 7) ^ (row & 7);
                gl_lds16(A + (size_t)(m0 + row) * K + kb + h * 64 + cl * 8,
                         &lA[h][(size_t)(p0 + wave * 64) * 8]);
            }
#pragma unroll
            for (int p0 = 0; p0 < BN * 8; p0 += 256) {
                int p = p0 + tid, row = p >> 3, cl = (p & 7) ^ (row & 7);
                gl_lds16(B + (size_t)(n0 + row) * K + kb + h * 64 + cl * 8,
                         &lB[h][(size_t)(p0 + wave * 64) * 8]);
            }
        }
        __syncthreads();
#pragma unroll
        for (int h = 0; h < NH; ++h)
#pragma unroll
            for (int k2 = 0; k2 < 2; ++k2) {
                bf16x8 af[MI], bfr[4];
#pragma unroll
                for (int t = 0; t < MI; ++t)
                    af[t] = *(const bf16x8*)&lA[h][(wrow + t * 16 + lc) * 64 + ((quad + k2 * 4) ^ swz) * 8];
#pragma unroll
                for (int t = 0; t < 4; ++t)
                    bfr[t] = *(const bf16x8*)&lB[h][(wcol + t * 16 + lc) * 64 + ((quad + k2 * 4) ^ swz) * 8];
#pragma unroll
                for (int mi = 0; mi < MI; ++mi)
#pragma unroll
                    for (int ni = 0; ni < 4; ++ni)
                        acc[mi][ni] = __builtin_amdgcn_mfma_f32_16x16x32_bf16(af[mi], bfr[ni],
                                                                             acc[mi][ni], 0, 0, 0);
            }
    }

#pragma unroll
    for (int mi = 0; mi < MI; ++mi) {
        int csa[4];
        if constexpr (EPI == 0) {
            int mbase = m0 + wrow + mi * 16 + quad * 4;
            int4 cs4 = *(const int4*)&cidx[(mbase >> 11) * SS + (mbase & 2047)];
            csa[0] = cs4.x; csa[1] = cs4.y; csa[2] = cs4.z; csa[3] = cs4.w;
        }
#pragma unroll
        for (int r = 0; r < 4; ++r) {
            int m = m0 + wrow + mi * 16 + quad * 4 + r;
#pragma unroll
            for (int ni = 0; ni < 4; ++ni) {
                int n = n0 + wcol + ni * 16 + lc;
                float v = acc[mi][ni][r];
                if constexpr (EPI == 0) {
                    int b = m >> 11, s = m & 2047;
                    int which = n / DD, rem = n - which * DD;
                    int h = rem >> 6, d = rem & 63;
                    u16* dst = which == 0 ? Qb : (which == 1 ? Kb : Vb);
                    int sidx = which == 0 ? s : csa[r];   // K/V: gather-compact
                    if (sidx >= 0)
                        dst[((((size_t)b * HH + h) * SS + sidx) << 6) + d] = f2bf(v);
                } else if constexpr (EPI == 1) {
                    // gelu_tanh(v) = v * sigmoid(2*0.79788456*(v + 0.044715 v^3))
                    float u = v * fmaf(v * v, 0.035677408f, 0.7978845608f);
                    float e = __builtin_amdgcn_exp2f(u * 2.885390082f);  // e^{2u}
                    float g = v - v * __builtin_amdgcn_rcpf(e + 1.0f);
                    ((u16*)out)[(size_t)m * N + n] = f2bf(g);
                } else if constexpr (EPI == 2) {
                    ((float*)out)[(size_t)m * N + n] =
                        v + ((const float*)aux)[(size_t)m * N + n];
                } else {
                    ((float*)out)[(size_t)m * N + n] =
                        v + (float)(((const __bf16*)aux)[(size_t)m * N + n]);
                }
            }
        }
    }
}

// ---------------- V transpose: compact [B,H,S,D] -> [B,H,D,S], zero-pad to 64 ----------------
__global__ __launch_bounds__(256) void transpose_v(const u16* __restrict__ V,
                                                   u16* __restrict__ Vt,
                                                   const int* __restrict__ cnt) {
    __shared__ u16 t[32][33];
    int bh = blockIdx.z;
    int c = cnt[bh / HH];
    int cr = (c + 63) & ~63;
    int s0 = blockIdx.x * 32, d0 = blockIdx.y * 32;
    if (s0 >= cr) return;
    const u16* vb = V + (size_t)bh * SS * HD;
    u16* vtb = Vt + (size_t)bh * HD * SS;
    int tx = threadIdx.x & 31, ty = threadIdx.x >> 5;
#pragma unroll
    for (int i = 0; i < 32; i += 8) {
        int s = s0 + ty + i;
        t[ty + i][tx] = (s < c) ? vb[(size_t)s * HD + d0 + tx] : (u16)0;
    }
    __syncthreads();
#pragma unroll
    for (int i = 0; i < 32; i += 8) vtb[(size_t)(d0 + ty + i) * SS + s0 + tx] = t[tx][ty + i];
}

// ---------------- flash attention over COMPACTED keys ----------------
// 256 threads (4 waves x 32q), grid 768 (3 blk/CU). K/V double-buffered with
// counted vmcnt(4) + raw barriers. Keys gathered to valid-only (~50%).
__global__ __launch_bounds__(256, 3) void attn_kernel(const u16* __restrict__ Q,
                                                      const u16* __restrict__ K,
                                                      const u16* __restrict__ Vt,
                                                      const int* __restrict__ cntg,
                                                      u16* __restrict__ Ctx) {
    __shared__ __align__(16) u16 lK[2][4096];
    __shared__ __align__(16) u16 lV[2][4096];   // [d][key]
    const int tid = threadIdx.x, lane = tid & 63, wave = tid >> 6;  // 4 waves
    const int quad = lane >> 4, lc = lane & 15;
    const int bh = blockIdx.x % (NB * HH);
    const int b = bh / HH, h = bh - b * HH;
    const int q0 = (blockIdx.x / (NB * HH)) * 128;
    const u16* Qg = Q + ((size_t)bh * SS + q0 + wave * 32) * HD;
    const u16* Kg = K + (size_t)bh * SS * HD;
    const u16* Vg = Vt + (size_t)bh * HD * SS;
    const int sw = lc & 7;
    const int cnt = cntg[b];
    const int nt = (cnt + 63) >> 6;

    const int srow = tid >> 3, scl = (tid & 7) ^ (srow & 7);
    const int srow2 = (256 + tid) >> 3, scl2 = (tid & 7) ^ (srow2 & 7);

    auto stage = [&](int bi, int j0) {
        gl_lds16(Kg + (size_t)(j0 + srow) * HD + scl * 8,   &lK[bi][(size_t)(wave * 64) * 8]);
        gl_lds16(Kg + (size_t)(j0 + srow2) * HD + scl2 * 8, &lK[bi][(size_t)(256 + wave * 64) * 8]);
        gl_lds16(Vg + (size_t)srow * SS + j0 + scl * 8,     &lV[bi][(size_t)(wave * 64) * 8]);
        gl_lds16(Vg + (size_t)srow2 * SS + j0 + scl2 * 8,   &lV[bi][(size_t)(256 + wave * 64) * 8]);
    };

    bf16x8 qf[2][2];
#pragma unroll
    for (int mi = 0; mi < 2; ++mi)
#pragma unroll
        for (int k2 = 0; k2 < 2; ++k2)
            qf[mi][k2] = *(const bf16x8*)(Qg + (size_t)(mi * 16 + lc) * HD + k2 * 32 + quad * 8);

    bf16x8 onesf;
#pragma unroll
    for (int i = 0; i < 8; ++i) onesf[i] = (__bf16)1.0f;

    f32x4 oacc[2][4] = {};
    f32x4 lsum[2] = {};

    stage(0, 0);
    for (int t = 0; t < nt; ++t) {
        const int cur = t & 1;
        if (t < nt - 1) {
            stage(cur ^ 1, (t + 1) * 64);
            __builtin_amdgcn_sched_barrier(0);
            asm volatile("s_waitcnt vmcnt(4)" ::: "memory");
        } else {
            __builtin_amdgcn_sched_barrier(0);
            asm volatile("s_waitcnt vmcnt(0)" ::: "memory");
        }
        __builtin_amdgcn_sched_barrier(0);
        __builtin_amdgcn_s_barrier();
        __builtin_amdgcn_sched_barrier(0);

        const u16* bK = &lK[cur][0];
        const u16* bV = &lV[cur][0];

        f32x4 sacc[2][4] = {};
        __builtin_amdgcn_s_setprio(1);
#pragma unroll
        for (int k2 = 0; k2 < 2; ++k2) {
            bf16x8 kf[4];
#pragma unroll
            for (int ni = 0; ni < 4; ++ni)
                kf[ni] = *(const bf16x8*)&bK[(ni * 16 + lc) * 64 + ((quad + k2 * 4) ^ sw) * 8];
#pragma unroll
            for (int ni = 0; ni < 4; ++ni) {
                sacc[0][ni] = __builtin_amdgcn_mfma_f32_16x16x32_bf16(kf[ni], qf[0][k2], sacc[0][ni], 0, 0, 0);
                sacc[1][ni] = __builtin_amdgcn_mfma_f32_16x16x32_bf16(kf[ni], qf[1][k2], sacc[1][ni], 0, 0, 0);
            }
        }
        __builtin_amdgcn_s_setprio(0);

        const int kb_ = cnt - t * 64;
        const bool part = kb_ < 64;
        u32 pa[2][4], pb[2][4];
#pragma unroll
        for (int ni = 0; ni < 4; ++ni) {
#pragma unroll
            for (int mi = 0; mi < 2; ++mi) {
#pragma unroll
                for (int r = 0; r < 4; ++r) {
                    float e = __builtin_amdgcn_exp2f(sacc[mi][ni][r] * 0.180336880f);
                    if (part) e = (ni * 16 + quad * 4 + r < kb_) ? e : 0.0f;
                    sacc[mi][ni][r] = e;
                }
                pa[mi][ni] = __builtin_amdgcn_perm(fas(sacc[mi][ni][1]), fas(sacc[mi][ni][0]), 0x07060302);
                pb[mi][ni] = __builtin_amdgcn_perm(fas(sacc[mi][ni][3]), fas(sacc[mi][ni][2]), 0x07060302);
            }
        }

        bf16x8 pf[2][2];
#pragma unroll
        for (int mi = 0; mi < 2; ++mi)
#pragma unroll
            for (int k2 = 0; k2 < 2; ++k2) {
                u32 xa = pa[mi][2 * k2], ya = pa[mi][2 * k2 + 1];
                u32 xb = pb[mi][2 * k2], yb = pb[mi][2 * k2 + 1];
                asm("v_permlane32_swap_b32 %0, %1" : "+v"(xa), "+v"(ya));
                asm("v_permlane16_swap_b32 %0, %1" : "+v"(xa), "+v"(ya));
                asm("v_permlane32_swap_b32 %0, %1" : "+v"(xb), "+v"(yb));
                asm("v_permlane16_swap_b32 %0, %1" : "+v"(xb), "+v"(yb));
                u32x4 pw = { xa, xb, ya, yb };
                pf[mi][k2] = __builtin_bit_cast(bf16x8, pw);
            }

        __builtin_amdgcn_s_setprio(1);
#pragma unroll
        for (int k2 = 0; k2 < 2; ++k2) {
            lsum[0] = __builtin_amdgcn_mfma_f32_16x16x32_bf16(pf[0][k2], onesf, lsum[0], 0, 0, 0);
            lsum[1] = __builtin_amdgcn_mfma_f32_16x16x32_bf16(pf[1][k2], onesf, lsum[1], 0, 0, 0);
#pragma unroll
            for (int ni = 0; ni < 4; ++ni) {
                bf16x8 vf = *(const bf16x8*)&bV[(ni * 16 + lc) * 64 + ((quad + k2 * 4) ^ sw) * 8];
                oacc[0][ni] = __builtin_amdgcn_mfma_f32_16x16x32_bf16(pf[0][k2], vf, oacc[0][ni], 0, 0, 0);
                oacc[1][ni] = __builtin_amdgcn_mfma_f32_16x16x32_bf16(pf[1][k2], vf, oacc[1][ni], 0, 0, 0);
            }
        }
        __builtin_amdgcn_s_setprio(0);

        __builtin_amdgcn_sched_barrier(0);
        __builtin_amdgcn_s_barrier();
    }

#pragma unroll
    for (int mi = 0; mi < 2; ++mi)
#pragma unroll
        for (int r = 0; r < 4; ++r) {
            float inv = 1.0f / lsum[mi][r];
            int s = q0 + wave * 32 + mi * 16 + quad * 4 + r;
            size_t base = ((size_t)(b * SS + s)) * DD + h * HD;
#pragma unroll
            for (int ni = 0; ni < 4; ++ni)
                Ctx[base + ni * 16 + lc] = f2bf(oacc[mi][ni][r] * inv);
        }
}

// ---------------- LayerNorm over 768, one block per row ----------------
__global__ __launch_bounds__(256) void ln_kernel(const float* __restrict__ in,
                                                 const float* __restrict__ g,
                                                 const float* __restrict__ bb,
                                                 u16* __restrict__ out_bf,
                                                 float* __restrict__ out_f) {
    const int row = blockIdx.x, tid = threadIdx.x;
    const float* x = in + (size_t)row * DD;
    float v0 = x[tid], v1 = x[tid + 256], v2 = x[tid + 512];
    float s = v0 + v1 + v2;
    float q = v0 * v0 + v1 * v1 + v2 * v2;
#pragma unroll
    for (int o = 1; o < 64; o <<= 1) {
        s += __shfl_xor(s, o);
        q += __shfl_xor(q, o);
    }
    __shared__ float rs[4], rq[4];
    int wave = tid >> 6;
    if ((tid & 63) == 0) { rs[wave] = s; rq[wave] = q; }
    __syncthreads();
    s = rs[0] + rs[1] + rs[2] + rs[3];
    q = rq[0] + rq[1] + rq[2] + rq[3];
    float mu = s * (1.0f / DD);
    float var = q * (1.0f / DD) - mu * mu;
    float rstd = rsqrtf(var + 1e-5f);
#pragma unroll
    for (int j = 0; j < 3; ++j) {
        int col = tid + j * 256;
        float v = (j == 0 ? v0 : (j == 1 ? v1 : v2));
        float y = (v - mu) * rstd * g[col] + bb[col];
        if (out_bf) out_bf[(size_t)row * DD + col] = f2bf(y);
        if (out_f) out_f[(size_t)row * DD + col] = y;
    }
}

extern "C" void kernel_launch(void* const* d_in, const int* in_sizes, int n_in,
                              void* d_out, int out_size, void* d_ws, size_t ws_size,
                              hipStream_t stream) {
    const float* X    = (const float*)d_in[0];
    const int*   mask = (const int*)d_in[1];
    const float* Wq   = (const float*)d_in[2];
    const float* Wk   = (const float*)d_in[3];
    const float* Wv   = (const float*)d_in[4];
    const float* Wo   = (const float*)d_in[5];
    const float* W1   = (const float*)d_in[6];
    const float* W2   = (const float*)d_in[7];
    const float* ln_g = (const float*)d_in[8];
    const float* ln_b = (const float*)d_in[9];
    float* out = (float*)d_out;

    char* ws = (char*)d_ws;
    size_t off = 0;
    auto alloc = [&](size_t bytes) {
        void* p = ws + off;
        off += (bytes + 255) & ~(size_t)255;
        return p;
    };
    u16*   Xbf   = (u16*)alloc((size_t)ROWS * DD * 2);       // reused as Ctx
    u16*   Wqkvb = (u16*)alloc((size_t)3 * DD * DD * 2);
    u16*   Wob   = (u16*)alloc((size_t)DD * DD * 2);
    u16*   W1b   = (u16*)alloc((size_t)4 * DD * DD * 2);
    u16*   W2b   = (u16*)alloc((size_t)4 * DD * DD * 2);
    int*   cidx  = (int*)alloc((size_t)NB * SS * 4);
    int*   cnt   = (int*)alloc(256);
    u16*   Qb    = (u16*)alloc((size_t)ROWS * DD * 2);       // Qb..Vtb reused as Gb
    u16*   Kb    = (u16*)alloc((size_t)ROWS * DD * 2);
    u16*   Vb    = (u16*)alloc((size_t)ROWS * DD * 2);
    u16*   Vtb   = (u16*)alloc((size_t)ROWS * DD * 2);
    float* resid = (float*)alloc((size_t)ROWS * DD * 4);     // reused as h2
    u16*   n1b   = (u16*)alloc((size_t)ROWS * DD * 2);
    u16*   Gb    = Qb;          // 8192*3072*2 = 4 * (8192*768*2) = Qb..Vtb
    u16*   Ctxb  = Xbf;
    float* h2    = resid;

    // fused casts + valid-key scan (13056 + NB blocks)
    prep_kernel<<<dim3(13056 + NB), dim3(256), 0, stream>>>(
        X, Wq, Wk, Wv, Wo, W1, W2, mask,
        Xbf, Wqkvb, Wob, W1b, W2b, cidx, cnt);

    // QKV projection: [8192, 2304], XCD-slab 1D grid; K/V gather-compacted
    gemm_bt<0, 128, 64><<<dim3((3 * DD / 128) * (ROWS / 128)), dim3(256), 0, stream>>>(
        Xbf, Wqkvb, ROWS, 3 * DD, DD, nullptr, nullptr, Qb, Kb, Vb, cidx);

    transpose_v<<<dim3(SS / 32, HD / 32, NB * HH), dim3(256), 0, stream>>>(Vb, Vtb, cnt);

    // 1D XCD-swizzled grid: id = qb*48 + bh; compacted keys
    attn_kernel<<<dim3((SS / 128) * (NB * HH)), dim3(256), 0, stream>>>(
        Qb, Kb, Vtb, cnt, Ctxb);

    // O projection + residual: resid = x + ctx @ Wo^T  (BK=128: 6 K-tiles)
    gemm_bt<2, 64, 128><<<dim3((DD / 64) * (ROWS / 128)), dim3(256), 0, stream>>>(
        Ctxb, Wob, ROWS, DD, DD, resid, X, nullptr, nullptr, nullptr, nullptr);

    ln_kernel<<<dim3(ROWS), dim3(256), 0, stream>>>(resid, ln_g, ln_b, n1b, nullptr);

    // FFN1 + GELU(tanh-form): [8192, 3072] bf16 (proven r4 structure)
    gemm_bt<1, 128, 64><<<dim3((4 * DD / 128) * (ROWS / 128)), dim3(256), 0, stream>>>(
        n1b, W1b, ROWS, 4 * DD, DD, Gb, nullptr, nullptr, nullptr, nullptr, nullptr);

    // FFN2 + residual: h2 = n1 + g @ W2^T  (BK=128: 24 K-tiles)
    gemm_bt<3, 64, 128><<<dim3((DD / 64) * (ROWS / 128)), dim3(256), 0, stream>>>(
        Gb, W2b, ROWS, DD, 4 * DD, h2, n1b, nullptr, nullptr, nullptr, nullptr);

    ln_kernel<<<dim3(ROWS), dim3(256), 0, stream>>>(h2, ln_g, ln_b, nullptr, out);
}